// Round 2
// baseline (739.910 us; speedup 1.0000x reference)
//
#include <hip/hip_runtime.h>

// Linear_AB_I8_DE_F32: y[m,n] = 0.01 * sum_k x8[m,k]*w8[n,k] + bias[n]
// M=4096, N=11008, K=4096. int8 values in int32 containers.
//
// R5: pull the LDS round-trip off the critical path.
//   - one-phase READ-AHEAD: each phase issues ds_reads for the NEXT phase's
//     MFMA (after bar1, before this phase's MFMA) -> LDS pipe works during
//     MFMA windows, lgkm wait before MFMA ~0.
//   - consumption-ordered stage units (A0=a0-rows, B0=b01-rows, B1=b23-rows,
//     A1=a1-rows via per-wave-load global row remap); uniform vmcnt(4) per
//     phase (never 0) forces exactly the unit staged 2 phases ago.
//   - 4 distinct named __shared__ buffers + static-parity 2-tile unroll ->
//     LLVM AA can disambiguate ds_reads from outstanding global_load_lds.
//   - register-double-buffered b01 (read at P4 for next tile; old copy still
//     consumed by M4).

#define M_DIM 4096
#define N_DIM 11008
#define K_DIM 4096
#define BM 256
#define BN 256
#define BK 128                  // bytes of K per tile (int8)
#define NT (K_DIM / BK)         // 32 K-tiles
#define ALPHA 0.01f

typedef __attribute__((ext_vector_type(4))) int i32x4;

static __device__ __forceinline__ int pack4(int4 v) {
    return (v.x & 0xff) | ((v.y & 0xff) << 8) |
           ((v.z & 0xff) << 16) | ((unsigned)(v.w & 0xff) << 24);
}

// ---------------- fused pack: 16 int32 -> 16 int8 per thread ----------------
__global__ __launch_bounds__(256) void pack_i8_kernel(
    const int4* __restrict__ x, int4* __restrict__ xout, int n16x,
    const int4* __restrict__ w, int4* __restrict__ wout, int n16_total)
{
    int i = blockIdx.x * blockDim.x + threadIdx.x;
    if (i >= n16_total) return;
    const int4* src;
    int4* dst;
    int idx;
    if (i < n16x) { src = x; dst = xout; idx = i; }
    else          { src = w; dst = wout; idx = i - n16x; }
    const int4* p = src + (size_t)4 * idx;
    int4 a = p[0], b = p[1], c = p[2], d = p[3];
    int4 r;
    r.x = pack4(a); r.y = pack4(b); r.z = pack4(c); r.w = pack4(d);
    dst[idx] = r;
}

// ---------------- GEMM ----------------
// stage unit: 16 KB = 16 8-row groups; each wave covers 2 groups (u_=0,1).
// group formulas (s_ = u_*8 + wave):
//   GA0: rows {0-63,128-191}    (a0-read rows)
//   GA1: rows {64-127,192-255}  (a1)
//   GB0: rows {0-31,64-95,128-159,192-223}   (b01)
//   GB1: rows {32-63,96-127,160-191,224-255} (b23)
#define GA0 (s_ + 8 * (s_ >> 3))
#define GA1 (8 + s_ + 8 * (s_ >> 3))
#define GB0 ((s_ & 3) + 8 * (s_ >> 2))
#define GB1 (4 + (s_ & 3) + 8 * (s_ >> 2))

#define STAGE(dstArr, srcB, T, GEXPR)                                          \
    _Pragma("unroll") for (int u_ = 0; u_ < 2; u_++) {                         \
        const int s_ = u_ * 8 + wave;                                          \
        const int G_ = (GEXPR);                                                \
        __builtin_amdgcn_global_load_lds(                                      \
            (const __attribute__((address_space(1))) void*)(                   \
                (srcB) + (size_t)(G_ * 8 + (lane >> 3)) * K_DIM +              \
                (size_t)(T) * BK + sch16),                                     \
            (__attribute__((address_space(3))) void*)((dstArr) + G_ * 1024 +   \
                                                      lane * 16),              \
            16, 0, 0);                                                         \
    }

#define READ_A(Arr, dst, IB)                                                   \
    _Pragma("unroll") for (int i_ = 0; i_ < 4; i_++)                           \
        _Pragma("unroll") for (int k_ = 0; k_ < 2; k_++)                       \
            dst[i_][k_] = *(const i32x4*)((Arr) + aoff[k_] + ((IB) + i_) * 2048);

#define READ_B(Arr, dst, JB)                                                   \
    _Pragma("unroll") for (int j_ = 0; j_ < 2; j_++)                           \
        _Pragma("unroll") for (int k_ = 0; k_ < 2; k_++)                       \
            dst[j_][k_] = *(const i32x4*)((Arr) + boff[k_] + ((JB) + j_) * 2048);

#define MFMA_G(af, bf, IB, JB)                                                 \
    __builtin_amdgcn_s_setprio(1);                                             \
    _Pragma("unroll") for (int i_ = 0; i_ < 4; i_++)                           \
        _Pragma("unroll") for (int j_ = 0; j_ < 2; j_++)                       \
            _Pragma("unroll") for (int k_ = 0; k_ < 2; k_++)                   \
                acc[(IB) + i_][(JB) + j_] =                                    \
                    __builtin_amdgcn_mfma_i32_16x16x64_i8(                     \
                        af[i_][k_], bf[j_][k_],                                \
                        acc[(IB) + i_][(JB) + j_], 0, 0, 0);                   \
    __builtin_amdgcn_s_setprio(0);

#define VMCNT_(N) asm volatile("s_waitcnt vmcnt(" #N ")" ::: "memory")
#define VMCNT(N) VMCNT_(N)

// One K-tile, 4 phases. CA/CB = current bufs, NA/NB = next bufs.
// B01C = b01 regs for this tile, B01N = for next. STG: stage tile T+1.
// NRD: read a0/b01 of tile T+1 at P4.
#define TILE(CA, CB, NA, NB, T, B01C, B01N, STG, NRD, V1, V2, V3, V4)          \
    {                                                                          \
        /* P1: stage A0(T+1); read b23(T); MFMA a0 x b01 */                    \
        if (STG) { STAGE(NA, Abase, (T) + 1, GA0); }                           \
        VMCNT(V1);                                                             \
        __builtin_amdgcn_s_barrier();                                          \
        READ_B(CB, rb23, 2);                                                   \
        MFMA_G(ra0, B01C, 0, 0);                                               \
        __builtin_amdgcn_s_barrier();                                          \
        /* P2: stage B0(T+1); read a1(T); MFMA a0 x b23 */                     \
        if (STG) { STAGE(NB, Bbase, (T) + 1, GB0); }                           \
        VMCNT(V2);                                                             \
        __builtin_amdgcn_s_barrier();                                          \
        READ_A(CA, ra1, 4);                                                    \
        MFMA_G(ra0, rb23, 0, 2);                                               \
        __builtin_amdgcn_s_barrier();                                          \
        /* P3: stage B1(T+1); MFMA a1 x b23 */                                 \
        if (STG) { STAGE(NB, Bbase, (T) + 1, GB1); }                           \
        VMCNT(V3);                                                             \
        __builtin_amdgcn_s_barrier();                                          \
        MFMA_G(ra1, rb23, 4, 2);                                               \
        __builtin_amdgcn_s_barrier();                                          \
        /* P4: stage A1(T+1); read a0/b01(T+1) from next bufs; MFMA a1xb01 */  \
        if (STG) { STAGE(NA, Abase, (T) + 1, GA1); }                           \
        VMCNT(V4);                                                             \
        __builtin_amdgcn_s_barrier();                                          \
        if (NRD) { READ_A(NA, ra0, 0); READ_B(NB, B01N, 0); }                  \
        MFMA_G(ra1, B01C, 4, 0);                                               \
        __builtin_amdgcn_s_barrier();                                          \
    }

__global__ __launch_bounds__(512, 2) void gemm_i8_kernel(
    const char* __restrict__ A,     // [M][K] int8 row-major
    const char* __restrict__ B,     // [N][K] int8 row-major
    const float* __restrict__ bias, // [N]
    float* __restrict__ C)          // [M][N] fp32
{
    __shared__ __attribute__((aligned(16))) char As0[BM * BK];
    __shared__ __attribute__((aligned(16))) char Bs0[BN * BK];
    __shared__ __attribute__((aligned(16))) char As1[BM * BK];
    __shared__ __attribute__((aligned(16))) char Bs1[BN * BK];

    const int tid   = threadIdx.x;
    const int lane  = tid & 63;
    const int wave  = tid >> 6;
    const int waveM = (wave >> 2) * 128;   // 2x4 wave grid: 128x64 per wave
    const int waveN = (wave & 3) * 64;
    const int lrow  = lane & 15;
    const int lquad = lane >> 4;

    // bijective XCD swizzle: 688 = 8 * 86. XCD x owns M-panels {2x, 2x+1};
    // consecutive local pairs share a B-panel.
    const int bid = blockIdx.x;
    const int xcd = bid & 7;
    const int loc = bid >> 3;              // 0..85
    const int bm  = (2 * xcd + (loc & 1)) * BM;
    const int bn  = (loc >> 1) * BN;

    // staging swizzle: LDS slot (row, p) holds global chunk p ^ (row&7);
    // per-lane global chunk offset (row&7 == lane>>3 within an 8-row group):
    const int sch16 = ((lane & 7) ^ ((lane >> 3) & 7)) << 4;
    const char* Abase = A + (size_t)bm * K_DIM;
    const char* Bbase = B + (size_t)bn * K_DIM;

    // frag read: global chunk (ks*4+lquad) of row r lives at slot
    // (ks*4+lquad)^(r&7); r&7 == lrow&7 for 16-aligned bases.
    int aoff[2], boff[2];
#pragma unroll
    for (int ks = 0; ks < 2; ks++) {
        const int pos = ((ks * 4 + lquad) ^ (lrow & 7)) << 4;
        aoff[ks] = (waveM + lrow) * BK + pos;
        boff[ks] = (waveN + lrow) * BK + pos;
    }

    i32x4 acc[8][4] = {};
    i32x4 ra0[4][2], ra1[4][2], rb01A[2][2], rb01B[2][2], rb23[2][2];

    // prologue: stage tile0 fully; drain; read tile0's a0 + b01.
    STAGE(As0, Abase, 0, GA0);
    STAGE(Bs0, Bbase, 0, GB0);
    STAGE(Bs0, Bbase, 0, GB1);
    STAGE(As0, Abase, 0, GA1);
    VMCNT(0);
    __builtin_amdgcn_s_barrier();
    READ_A(As0, ra0, 0);
    READ_B(Bs0, rb01A, 0);

#pragma unroll 1
    for (int t = 0; t < NT - 2; t += 2) {
        TILE(As0, Bs0, As1, Bs1, t,     rb01A, rb01B, 1, 1, 4, 4, 4, 4);
        TILE(As1, Bs1, As0, Bs0, t + 1, rb01B, rb01A, 1, 1, 4, 4, 4, 4);
    }
    TILE(As0, Bs0, As1, Bs1, NT - 2, rb01A, rb01B, 1, 1, 4, 4, 4, 4);
    TILE(As1, Bs1, As0, Bs0, NT - 1, rb01B, rb01A, 0, 0, 2, 0, 0, 0);

    // epilogue: C/D layout col=lane&15, row=(lane>>4)*4+reg
#pragma unroll
    for (int i = 0; i < 8; i++) {
        const int r0 = bm + waveM + i * 16 + lquad * 4;
#pragma unroll
        for (int j = 0; j < 4; j++) {
            const int c0 = bn + waveN + j * 16 + lrow;
            const float bv = bias[c0];
#pragma unroll
            for (int r = 0; r < 4; r++) {
                C[(size_t)(r0 + r) * N_DIM + c0] = ALPHA * (float)acc[i][j][r] + bv;
            }
        }
    }
}

extern "C" void kernel_launch(void* const* d_in, const int* in_sizes, int n_in,
                              void* d_out, int out_size, void* d_ws, size_t ws_size,
                              hipStream_t stream) {
    const int*   x    = (const int*)d_in[0];
    const int*   w    = (const int*)d_in[1];
    const float* bias = (const float*)d_in[2];
    float*       out  = (float*)d_out;

    char* Ap = (char*)d_ws;
    char* Wp = (char*)d_ws + (size_t)M_DIM * K_DIM;

    const int n16x = M_DIM * K_DIM / 16;          // 1,048,576
    const int n16w = N_DIM * K_DIM / 16;          // 2,818,048
    const int n16  = n16x + n16w;                 // 3,866,624 -> 15104 blocks
    pack_i8_kernel<<<n16 / 256, 256, 0, stream>>>(
        (const int4*)x, (int4*)Ap, n16x, (const int4*)w, (int4*)Wp, n16);

    // 688 blocks = 8 XCDs x 86 (bijective swizzle inside the kernel)
    gemm_i8_kernel<<<dim3((M_DIM / BM) * (N_DIM / BN)), 512, 0, stream>>>(
        Ap, Wp, bias, out);
}

// Round 3
// 739.146 us; speedup vs baseline: 1.0010x; 1.0010x over previous
//
#include <hip/hip_runtime.h>

// Linear_AB_I8_DE_F32: y[m,n] = 0.01 * sum_k x8[m,k]*w8[n,k] + bias[n]
// M=4096, N=11008, K=4096. int8 values in int32 containers.
//
// R6: R5's read-ahead schedule, register-pressure fixed.
//   - __launch_bounds__(512, 1): LDS (128 KiB) already limits to 1 block/CU;
//     the old ",2" capped VGPRs at 128 (acc alone is 128) -> R5 spilled
//     ~380 MB of scratch traffic per dispatch. Budget is now 256/wave.
//   - B-fragment parity role-swap: tile T uses B01=alpha, B23=beta; P4's
//     read-ahead writes b01(T+1) into beta (dead after P3). 2 b-buffers
//     instead of 3. Frag total: 128 acc + 64 a + 32 b = 224 VGPR.
//   - one-phase READ-AHEAD kept: each phase's ds_reads feed the NEXT MFMA.
//   - consumption-ordered stage units + uniform vmcnt(4) per phase kept.
//   - 4 distinct named __shared__ buffers + static-parity 2-tile unroll kept.

#define M_DIM 4096
#define N_DIM 11008
#define K_DIM 4096
#define BM 256
#define BN 256
#define BK 128                  // bytes of K per tile (int8)
#define NT (K_DIM / BK)         // 32 K-tiles
#define ALPHA 0.01f

typedef __attribute__((ext_vector_type(4))) int i32x4;

static __device__ __forceinline__ int pack4(int4 v) {
    return (v.x & 0xff) | ((v.y & 0xff) << 8) |
           ((v.z & 0xff) << 16) | ((unsigned)(v.w & 0xff) << 24);
}

// ---------------- fused pack: 16 int32 -> 16 int8 per thread ----------------
__global__ __launch_bounds__(256) void pack_i8_kernel(
    const int4* __restrict__ x, int4* __restrict__ xout, int n16x,
    const int4* __restrict__ w, int4* __restrict__ wout, int n16_total)
{
    int i = blockIdx.x * blockDim.x + threadIdx.x;
    if (i >= n16_total) return;
    const int4* src;
    int4* dst;
    int idx;
    if (i < n16x) { src = x; dst = xout; idx = i; }
    else          { src = w; dst = wout; idx = i - n16x; }
    const int4* p = src + (size_t)4 * idx;
    int4 a = p[0], b = p[1], c = p[2], d = p[3];
    int4 r;
    r.x = pack4(a); r.y = pack4(b); r.z = pack4(c); r.w = pack4(d);
    dst[idx] = r;
}

// ---------------- GEMM ----------------
// stage unit: 16 KB = 16 8-row groups; each wave covers 2 groups (u_=0,1).
// group formulas (s_ = u_*8 + wave):
//   GA0: rows {0-63,128-191}    (a0-read rows)
//   GA1: rows {64-127,192-255}  (a1)
//   GB0: rows {0-31,64-95,128-159,192-223}   (b01)
//   GB1: rows {32-63,96-127,160-191,224-255} (b23)
#define GA0 (s_ + 8 * (s_ >> 3))
#define GA1 (8 + s_ + 8 * (s_ >> 3))
#define GB0 ((s_ & 3) + 8 * (s_ >> 2))
#define GB1 (4 + (s_ & 3) + 8 * (s_ >> 2))

#define STAGE(dstArr, srcB, T, GEXPR)                                          \
    _Pragma("unroll") for (int u_ = 0; u_ < 2; u_++) {                         \
        const int s_ = u_ * 8 + wave;                                          \
        const int G_ = (GEXPR);                                                \
        __builtin_amdgcn_global_load_lds(                                      \
            (const __attribute__((address_space(1))) void*)(                   \
                (srcB) + (size_t)(G_ * 8 + (lane >> 3)) * K_DIM +              \
                (size_t)(T) * BK + sch16),                                     \
            (__attribute__((address_space(3))) void*)((dstArr) + G_ * 1024 +   \
                                                      lane * 16),              \
            16, 0, 0);                                                         \
    }

#define READ_A(Arr, dst, IB)                                                   \
    _Pragma("unroll") for (int i_ = 0; i_ < 4; i_++)                           \
        _Pragma("unroll") for (int k_ = 0; k_ < 2; k_++)                       \
            dst[i_][k_] = *(const i32x4*)((Arr) + aoff[k_] + ((IB) + i_) * 2048);

#define READ_B(Arr, dst, JB)                                                   \
    _Pragma("unroll") for (int j_ = 0; j_ < 2; j_++)                           \
        _Pragma("unroll") for (int k_ = 0; k_ < 2; k_++)                       \
            dst[j_][k_] = *(const i32x4*)((Arr) + boff[k_] + ((JB) + j_) * 2048);

#define MFMA_G(af, bf, IB, JB)                                                 \
    __builtin_amdgcn_s_setprio(1);                                             \
    _Pragma("unroll") for (int i_ = 0; i_ < 4; i_++)                           \
        _Pragma("unroll") for (int j_ = 0; j_ < 2; j_++)                       \
            _Pragma("unroll") for (int k_ = 0; k_ < 2; k_++)                   \
                acc[(IB) + i_][(JB) + j_] =                                    \
                    __builtin_amdgcn_mfma_i32_16x16x64_i8(                     \
                        af[i_][k_], bf[j_][k_],                                \
                        acc[(IB) + i_][(JB) + j_], 0, 0, 0);                   \
    __builtin_amdgcn_s_setprio(0);

#define VMCNT_(N) asm volatile("s_waitcnt vmcnt(" #N ")" ::: "memory")
#define VMCNT(N) VMCNT_(N)

// One K-tile, 4 phases. CA/CB = current bufs, NA/NB = next bufs.
// B01/B23 = b fragment buffers for this tile (parity-swapped per tile);
// P4's read-ahead writes b01(T+1) into B23 (dead after P3's MFMA).
// STG: stage tile T+1. NRD: read a0/b01 of tile T+1 at P4.
#define TILE(CA, CB, NA, NB, T, B01, B23, STG, NRD, V1, V2, V3, V4)            \
    {                                                                          \
        /* P1: stage A0(T+1); read b23(T); MFMA a0 x b01 */                    \
        if (STG) { STAGE(NA, Abase, (T) + 1, GA0); }                           \
        VMCNT(V1);                                                             \
        __builtin_amdgcn_s_barrier();                                          \
        READ_B(CB, B23, 2);                                                    \
        MFMA_G(ra0, B01, 0, 0);                                                \
        __builtin_amdgcn_s_barrier();                                          \
        /* P2: stage B0(T+1); read a1(T); MFMA a0 x b23 */                     \
        if (STG) { STAGE(NB, Bbase, (T) + 1, GB0); }                           \
        VMCNT(V2);                                                             \
        __builtin_amdgcn_s_barrier();                                          \
        READ_A(CA, ra1, 4);                                                    \
        MFMA_G(ra0, B23, 0, 2);                                                \
        __builtin_amdgcn_s_barrier();                                          \
        /* P3: stage B1(T+1); MFMA a1 x b23 */                                 \
        if (STG) { STAGE(NB, Bbase, (T) + 1, GB1); }                           \
        VMCNT(V3);                                                             \
        __builtin_amdgcn_s_barrier();                                          \
        MFMA_G(ra1, B23, 4, 2);                                                \
        __builtin_amdgcn_s_barrier();                                          \
        /* P4: stage A1(T+1); read a0(T+1) + b01(T+1) -> B23 regs; MFMA */     \
        if (STG) { STAGE(NA, Abase, (T) + 1, GA1); }                           \
        VMCNT(V4);                                                             \
        __builtin_amdgcn_s_barrier();                                          \
        if (NRD) { READ_A(NA, ra0, 0); READ_B(NB, B23, 0); }                   \
        MFMA_G(ra1, B01, 4, 0);                                                \
        __builtin_amdgcn_s_barrier();                                          \
    }

__global__ __launch_bounds__(512, 1) void gemm_i8_kernel(
    const char* __restrict__ A,     // [M][K] int8 row-major
    const char* __restrict__ B,     // [N][K] int8 row-major
    const float* __restrict__ bias, // [N]
    float* __restrict__ C)          // [M][N] fp32
{
    __shared__ __attribute__((aligned(16))) char As0[BM * BK];
    __shared__ __attribute__((aligned(16))) char Bs0[BN * BK];
    __shared__ __attribute__((aligned(16))) char As1[BM * BK];
    __shared__ __attribute__((aligned(16))) char Bs1[BN * BK];

    const int tid   = threadIdx.x;
    const int lane  = tid & 63;
    const int wave  = tid >> 6;
    const int waveM = (wave >> 2) * 128;   // 2x4 wave grid: 128x64 per wave
    const int waveN = (wave & 3) * 64;
    const int lrow  = lane & 15;
    const int lquad = lane >> 4;

    // bijective XCD swizzle: 688 = 8 * 86. XCD x owns M-panels {2x, 2x+1};
    // consecutive local pairs share a B-panel.
    const int bid = blockIdx.x;
    const int xcd = bid & 7;
    const int loc = bid >> 3;              // 0..85
    const int bm  = (2 * xcd + (loc & 1)) * BM;
    const int bn  = (loc >> 1) * BN;

    // staging swizzle: LDS slot (row, p) holds global chunk p ^ (row&7);
    // per-lane global chunk offset (row&7 == lane>>3 within an 8-row group):
    const int sch16 = ((lane & 7) ^ ((lane >> 3) & 7)) << 4;
    const char* Abase = A + (size_t)bm * K_DIM;
    const char* Bbase = B + (size_t)bn * K_DIM;

    // frag read: global chunk (ks*4+lquad) of row r lives at slot
    // (ks*4+lquad)^(r&7); r&7 == lrow&7 for 16-aligned bases.
    int aoff[2], boff[2];
#pragma unroll
    for (int ks = 0; ks < 2; ks++) {
        const int pos = ((ks * 4 + lquad) ^ (lrow & 7)) << 4;
        aoff[ks] = (waveM + lrow) * BK + pos;
        boff[ks] = (waveN + lrow) * BK + pos;
    }

    i32x4 acc[8][4] = {};
    i32x4 ra0[4][2], ra1[4][2], rbA[2][2], rbB[2][2];

    // prologue: stage tile0 fully; drain; read tile0's a0 + b01 (-> rbA).
    STAGE(As0, Abase, 0, GA0);
    STAGE(Bs0, Bbase, 0, GB0);
    STAGE(Bs0, Bbase, 0, GB1);
    STAGE(As0, Abase, 0, GA1);
    VMCNT(0);
    __builtin_amdgcn_s_barrier();
    READ_A(As0, ra0, 0);
    READ_B(Bs0, rbA, 0);

#pragma unroll 1
    for (int t = 0; t < NT - 2; t += 2) {
        TILE(As0, Bs0, As1, Bs1, t,     rbA, rbB, 1, 1, 4, 4, 4, 4);
        TILE(As1, Bs1, As0, Bs0, t + 1, rbB, rbA, 1, 1, 4, 4, 4, 4);
    }
    TILE(As0, Bs0, As1, Bs1, NT - 2, rbA, rbB, 1, 1, 4, 4, 4, 4);
    TILE(As1, Bs1, As0, Bs0, NT - 1, rbB, rbA, 0, 0, 2, 0, 0, 0);

    // epilogue: C/D layout col=lane&15, row=(lane>>4)*4+reg
#pragma unroll
    for (int i = 0; i < 8; i++) {
        const int r0 = bm + waveM + i * 16 + lquad * 4;
#pragma unroll
        for (int j = 0; j < 4; j++) {
            const int c0 = bn + waveN + j * 16 + lrow;
            const float bv = bias[c0];
#pragma unroll
            for (int r = 0; r < 4; r++) {
                C[(size_t)(r0 + r) * N_DIM + c0] = ALPHA * (float)acc[i][j][r] + bv;
            }
        }
    }
}

extern "C" void kernel_launch(void* const* d_in, const int* in_sizes, int n_in,
                              void* d_out, int out_size, void* d_ws, size_t ws_size,
                              hipStream_t stream) {
    const int*   x    = (const int*)d_in[0];
    const int*   w    = (const int*)d_in[1];
    const float* bias = (const float*)d_in[2];
    float*       out  = (float*)d_out;

    char* Ap = (char*)d_ws;
    char* Wp = (char*)d_ws + (size_t)M_DIM * K_DIM;

    const int n16x = M_DIM * K_DIM / 16;          // 1,048,576
    const int n16w = N_DIM * K_DIM / 16;          // 2,818,048
    const int n16  = n16x + n16w;                 // 3,866,624 -> 15104 blocks
    pack_i8_kernel<<<n16 / 256, 256, 0, stream>>>(
        (const int4*)x, (int4*)Ap, n16x, (const int4*)w, (int4*)Wp, n16);

    // 688 blocks = 8 XCDs x 86 (bijective swizzle inside the kernel)
    gemm_i8_kernel<<<dim3((M_DIM / BM) * (N_DIM / BN)), 512, 0, stream>>>(
        Ap, Wp, bias, out);
}

// Round 4
// 541.553 us; speedup vs baseline: 1.3663x; 1.3649x over previous
//
#include <hip/hip_runtime.h>

// Linear_AB_I8_DE_F32: y[m,n] = 0.01 * sum_k x8[m,k]*w8[n,k] + bias[n]
// M=4096, N=11008, K=4096. int8 values in int32 containers.
//
// R7: m201-faithful generation-guarded pipeline at R4's register cost.
//   - phase-local fragments only (a0,a1,b01,b23; b01 re-read at P4):
//     max live ~64 frag regs -> arch VGPR ~100 <= the hard 128 ceiling
//     (8-wave block = 2 waves/SIMD = 256 unified; acc=128 AGPR fixed).
//   - 2 stage-loads per phase (P1:A0', P2:B0', P3:B1', P4:A1'), uniform
//     vmcnt(6) per phase: unit staged at phase q is confirmed by the
//     vmcnt at q+3 (8 outstanding -> 6 retires the 2 oldest), and the
//     following s_barrier makes it visible to ALL waves -> reads at q+3
//     (late, post-bar) or q+4 (early, pre-bar) are race-free.
//   - early reads (a0 @P1, b01-reread @P4) issue pre-bar1: LDS latency
//     overlaps barrier convergence. Late reads sit right after bar1.
//   - 4 named LDS buffers + static-parity 2-tile unroll (LLVM AA can
//     disambiguate ds_reads from in-flight global_load_lds writes).
//   - tail tile vmcnt (4,2,0,0); no vmcnt(0) anywhere in steady state.

#define M_DIM 4096
#define N_DIM 11008
#define K_DIM 4096
#define BM 256
#define BN 256
#define BK 128                  // bytes of K per tile (int8)
#define NT (K_DIM / BK)         // 32 K-tiles
#define ALPHA 0.01f

typedef __attribute__((ext_vector_type(4))) int i32x4;

static __device__ __forceinline__ int pack4(int4 v) {
    return (v.x & 0xff) | ((v.y & 0xff) << 8) |
           ((v.z & 0xff) << 16) | ((unsigned)(v.w & 0xff) << 24);
}

// ---------------- fused pack: 16 int32 -> 16 int8 per thread ----------------
__global__ __launch_bounds__(256) void pack_i8_kernel(
    const int4* __restrict__ x, int4* __restrict__ xout, int n16x,
    const int4* __restrict__ w, int4* __restrict__ wout, int n16_total)
{
    int i = blockIdx.x * blockDim.x + threadIdx.x;
    if (i >= n16_total) return;
    const int4* src;
    int4* dst;
    int idx;
    if (i < n16x) { src = x; dst = xout; idx = i; }
    else          { src = w; dst = wout; idx = i - n16x; }
    const int4* p = src + (size_t)4 * idx;
    int4 a = p[0], b = p[1], c = p[2], d = p[3];
    int4 r;
    r.x = pack4(a); r.y = pack4(b); r.z = pack4(c); r.w = pack4(d);
    dst[idx] = r;
}

// ---------------- GEMM ----------------
// stage unit: 16 KB = 16 8-row groups; each wave covers 2 groups (u_=0,1).
// group formulas (s_ = u_*8 + wave):
//   GA0: rows {0-63,128-191}    (a0-read rows)
//   GA1: rows {64-127,192-255}  (a1)
//   GB0: rows {0-31,64-95,128-159,192-223}   (b01)
//   GB1: rows {32-63,96-127,160-191,224-255} (b23)
#define GA0 (s_ + 8 * (s_ >> 3))
#define GA1 (8 + s_ + 8 * (s_ >> 3))
#define GB0 ((s_ & 3) + 8 * (s_ >> 2))
#define GB1 (4 + (s_ & 3) + 8 * (s_ >> 2))

#define STAGE(dstArr, srcB, T, GEXPR)                                          \
    _Pragma("unroll") for (int u_ = 0; u_ < 2; u_++) {                         \
        const int s_ = u_ * 8 + wave;                                          \
        const int G_ = (GEXPR);                                                \
        __builtin_amdgcn_global_load_lds(                                      \
            (const __attribute__((address_space(1))) void*)(                   \
                (srcB) + (size_t)(G_ * 8 + (lane >> 3)) * K_DIM +              \
                (size_t)(T) * BK + sch16),                                     \
            (__attribute__((address_space(3))) void*)((dstArr) + G_ * 1024 +   \
                                                      lane * 16),              \
            16, 0, 0);                                                         \
    }

#define READ_A(Arr, dst, IB)                                                   \
    _Pragma("unroll") for (int i_ = 0; i_ < 4; i_++)                           \
        _Pragma("unroll") for (int k_ = 0; k_ < 2; k_++)                       \
            dst[i_][k_] = *(const i32x4*)((Arr) + aoff[k_] + ((IB) + i_) * 2048);

#define READ_B(Arr, dst, JB)                                                   \
    _Pragma("unroll") for (int j_ = 0; j_ < 2; j_++)                           \
        _Pragma("unroll") for (int k_ = 0; k_ < 2; k_++)                       \
            dst[j_][k_] = *(const i32x4*)((Arr) + boff[k_] + ((JB) + j_) * 2048);

#define MFMA_G(af, bf, IB, JB)                                                 \
    __builtin_amdgcn_s_setprio(1);                                             \
    _Pragma("unroll") for (int i_ = 0; i_ < 4; i_++)                           \
        _Pragma("unroll") for (int j_ = 0; j_ < 2; j_++)                       \
            _Pragma("unroll") for (int k_ = 0; k_ < 2; k_++)                   \
                acc[(IB) + i_][(JB) + j_] =                                    \
                    __builtin_amdgcn_mfma_i32_16x16x64_i8(                     \
                        af[i_][k_], bf[j_][k_],                                \
                        acc[(IB) + i_][(JB) + j_], 0, 0, 0);                   \
    __builtin_amdgcn_s_setprio(0);

#define VMCNT_(N) asm volatile("s_waitcnt vmcnt(" #N ")" ::: "memory")
#define VMCNT(N) VMCNT_(N)
#define BAR() __builtin_amdgcn_s_barrier()

// One K-tile, 4 phases. CA/CB = current read bufs, NA/NB = stage-dest bufs.
// STG: stage tile T+1. V1..V4: per-phase vmcnt gates.
#define TILE(CA, CB, NA, NB, T, STG, V1, V2, V3, V4)                           \
    {                                                                          \
        /* P1: early a0 | stage A0(T+1) | gate B0(T) | late b01 | MFMA */      \
        READ_A(CA, ra0, 0);                                                    \
        if (STG) { STAGE(NA, Abase, (T) + 1, GA0); }                           \
        VMCNT(V1);                                                             \
        BAR();                                                                 \
        READ_B(CB, rb01, 0);                                                   \
        MFMA_G(ra0, rb01, 0, 0);                                               \
        BAR();                                                                 \
        /* P2: stage B0(T+1) | gate B1(T) | late b23 | MFMA */                 \
        if (STG) { STAGE(NB, Bbase, (T) + 1, GB0); }                           \
        VMCNT(V2);                                                             \
        BAR();                                                                 \
        READ_B(CB, rb23, 2);                                                   \
        MFMA_G(ra0, rb23, 0, 2);                                               \
        BAR();                                                                 \
        /* P3: stage B1(T+1) | gate A1(T) | late a1 | MFMA */                  \
        if (STG) { STAGE(NB, Bbase, (T) + 1, GB1); }                           \
        VMCNT(V3);                                                             \
        BAR();                                                                 \
        READ_A(CA, ra1, 4);                                                    \
        MFMA_G(ra1, rb23, 4, 2);                                               \
        BAR();                                                                 \
        /* P4: early b01 re-read | stage A1(T+1) | gate | MFMA */              \
        READ_B(CB, rb01, 0);                                                   \
        if (STG) { STAGE(NA, Abase, (T) + 1, GA1); }                           \
        VMCNT(V4);                                                             \
        BAR();                                                                 \
        MFMA_G(ra1, rb01, 4, 0);                                               \
        BAR();                                                                 \
    }

__global__ __launch_bounds__(512, 1) void gemm_i8_kernel(
    const char* __restrict__ A,     // [M][K] int8 row-major
    const char* __restrict__ B,     // [N][K] int8 row-major
    const float* __restrict__ bias, // [N]
    float* __restrict__ C)          // [M][N] fp32
{
    __shared__ __attribute__((aligned(16))) char As0[BM * BK];
    __shared__ __attribute__((aligned(16))) char Bs0[BN * BK];
    __shared__ __attribute__((aligned(16))) char As1[BM * BK];
    __shared__ __attribute__((aligned(16))) char Bs1[BN * BK];

    const int tid   = threadIdx.x;
    const int lane  = tid & 63;
    const int wave  = tid >> 6;
    const int waveM = (wave >> 2) * 128;   // 2x4 wave grid: 128x64 per wave
    const int waveN = (wave & 3) * 64;
    const int lrow  = lane & 15;
    const int lquad = lane >> 4;

    // bijective XCD swizzle: 688 = 8 * 86. XCD x owns M-panels {2x, 2x+1};
    // consecutive local pairs share a B-panel.
    const int bid = blockIdx.x;
    const int xcd = bid & 7;
    const int loc = bid >> 3;              // 0..85
    const int bm  = (2 * xcd + (loc & 1)) * BM;
    const int bn  = (loc >> 1) * BN;

    // staging swizzle: LDS slot (row, p) holds global chunk p ^ (row&7);
    // per-lane global chunk offset (row&7 == lane>>3 within an 8-row group):
    const int sch16 = ((lane & 7) ^ ((lane >> 3) & 7)) << 4;
    const char* Abase = A + (size_t)bm * K_DIM;
    const char* Bbase = B + (size_t)bn * K_DIM;

    // frag read: global chunk (ks*4+lquad) of row r lives at slot
    // (ks*4+lquad)^(r&7); r&7 == lrow&7 for 16-aligned bases.
    int aoff[2], boff[2];
#pragma unroll
    for (int ks = 0; ks < 2; ks++) {
        const int pos = ((ks * 4 + lquad) ^ (lrow & 7)) << 4;
        aoff[ks] = (waveM + lrow) * BK + pos;
        boff[ks] = (waveN + lrow) * BK + pos;
    }

    i32x4 acc[8][4] = {};
    i32x4 ra0[4][2], ra1[4][2], rb01[2][2], rb23[2][2];

    // prologue: stage tile0 fully; drain once; enter steady state.
    STAGE(As0, Abase, 0, GA0);
    STAGE(Bs0, Bbase, 0, GB0);
    STAGE(Bs0, Bbase, 0, GB1);
    STAGE(As0, Abase, 0, GA1);
    VMCNT(0);
    BAR();

#pragma unroll 1
    for (int t = 0; t < NT - 2; t += 2) {
        TILE(As0, Bs0, As1, Bs1, t,     1, 6, 6, 6, 6);
        TILE(As1, Bs1, As0, Bs0, t + 1, 1, 6, 6, 6, 6);
    }
    TILE(As0, Bs0, As1, Bs1, NT - 2, 1, 6, 6, 6, 6);
    TILE(As1, Bs1, As0, Bs0, NT - 1, 0, 4, 2, 0, 0);

    // epilogue: C/D layout col=lane&15, row=(lane>>4)*4+reg
#pragma unroll
    for (int i = 0; i < 8; i++) {
        const int r0 = bm + waveM + i * 16 + lquad * 4;
#pragma unroll
        for (int j = 0; j < 4; j++) {
            const int c0 = bn + waveN + j * 16 + lrow;
            const float bv = bias[c0];
#pragma unroll
            for (int r = 0; r < 4; r++) {
                C[(size_t)(r0 + r) * N_DIM + c0] = ALPHA * (float)acc[i][j][r] + bv;
            }
        }
    }
}

extern "C" void kernel_launch(void* const* d_in, const int* in_sizes, int n_in,
                              void* d_out, int out_size, void* d_ws, size_t ws_size,
                              hipStream_t stream) {
    const int*   x    = (const int*)d_in[0];
    const int*   w    = (const int*)d_in[1];
    const float* bias = (const float*)d_in[2];
    float*       out  = (float*)d_out;

    char* Ap = (char*)d_ws;
    char* Wp = (char*)d_ws + (size_t)M_DIM * K_DIM;

    const int n16x = M_DIM * K_DIM / 16;          // 1,048,576
    const int n16w = N_DIM * K_DIM / 16;          // 2,818,048
    const int n16  = n16x + n16w;                 // 3,866,624 -> 15104 blocks
    pack_i8_kernel<<<n16 / 256, 256, 0, stream>>>(
        (const int4*)x, (int4*)Ap, n16x, (const int4*)w, (int4*)Wp, n16);

    // 688 blocks = 8 XCDs x 86 (bijective swizzle inside the kernel)
    gemm_i8_kernel<<<dim3((M_DIM / BM) * (N_DIM / BN)), 512, 0, stream>>>(
        Ap, Wp, bias, out);
}